// Round 9
// baseline (582.232 us; speedup 1.0000x reference)
//
#include <hip/hip_runtime.h>
#include <hip/hip_fp16.h>

#define N 16384
#define CAP 64   // max tracked nnz per row/col of H (Poisson(17) -> max ~40)

typedef float f4 __attribute__((ext_vector_type(4)));

// ---------------------------------------------------------------------------
// init: zero col_cnt.
__global__ void k_init(int* __restrict__ col_cnt) {
    col_cnt[blockIdx.x * 256 + threadIdx.x] = 0;
}

// ---------------------------------------------------------------------------
// Mega kernel:
//   blocks [0,2048):        first feature GEMM (x @ th0 + b0 -> F1h, fp16)
//   blocks [2048, 2048+N):  stream one row of dense H each -> CSR + CSC
//   block  2048+N:          coefficient folding (hidden under the scan):
//       P = th1 @ w1 @ w2 (128x128), e = w2^T w1^T b1, d = w2^T bw1 + bw2,
//       ab = collapsed label-branch affine coefficients.
__global__ void k_mega(const float* __restrict__ H,
                       int* __restrict__ row_cnt, int* __restrict__ col_cnt,
                       int* __restrict__ rowIdx, int* __restrict__ colIdx,
                       const float* __restrict__ x, const float* __restrict__ th0,
                       const float* __restrict__ b0, __half* __restrict__ F1h,
                       const float* __restrict__ th1, const float* __restrict__ b1,
                       const float* __restrict__ w1, const float* __restrict__ w2,
                       const float* __restrict__ bw1, const float* __restrict__ bw2,
                       const float* __restrict__ lt0, const float* __restrict__ lb0,
                       const float* __restrict__ lt1, const float* __restrict__ lb1,
                       const float* __restrict__ fcw, const float* __restrict__ fcb,
                       float* __restrict__ ab, float* __restrict__ wsT,
                       float* __restrict__ wsP, float* __restrict__ evec,
                       float* __restrict__ dvec, float* __restrict__ wsV1) {
    if (blockIdx.x < 2048) {
        __shared__ float xs[8][128];
        int tid = threadIdx.x;
        int r0 = blockIdx.x * 8;
        {
            int i = tid * 4, rr = i >> 7, kk = i & 127;
            f4 raw = *reinterpret_cast<const f4*>(x + (size_t)(r0 + rr) * 128 + kk);
            xs[rr][kk] = raw.x; xs[rr][kk + 1] = raw.y;
            xs[rr][kk + 2] = raw.z; xs[rr][kk + 3] = raw.w;
        }
        __syncthreads();
        int g = tid >> 5, c4 = tid & 31;
        f4 acc = *reinterpret_cast<const f4*>(b0 + c4 * 4);
        #pragma unroll 8
        for (int k = 0; k < 128; ++k) {
            f4 w = *reinterpret_cast<const f4*>(th0 + (size_t)k * 128 + c4 * 4);
            acc += xs[g][k] * w;
        }
        uint2 o;
        __half2* oh = reinterpret_cast<__half2*>(&o);
        oh[0] = __floats2half2_rn(acc.x, acc.y);
        oh[1] = __floats2half2_rn(acc.z, acc.w);
        *reinterpret_cast<uint2*>(F1h + (size_t)(r0 + g) * 128 + c4 * 4) = o;
    } else if (blockIdx.x < 2048 + N) {
        __shared__ int rc;
        int v = blockIdx.x - 2048;
        if (threadIdx.x == 0) rc = 0;
        __syncthreads();
        const f4* row = reinterpret_cast<const f4*>(H + (size_t)v * N);
        #pragma unroll 4
        for (int i = 0; i < 16; ++i) {
            int idx4 = i * 256 + threadIdx.x;
            f4 val = __builtin_nontemporal_load(row + idx4);
            int e0 = idx4 * 4;
            float vals[4] = {val.x, val.y, val.z, val.w};
            #pragma unroll
            for (int j = 0; j < 4; ++j) {
                if (vals[j] != 0.0f) {
                    int e = e0 + j;
                    int p = atomicAdd(&rc, 1);
                    if (p < CAP) rowIdx[(size_t)v * CAP + p] = e;
                    int q = atomicAdd(&col_cnt[e], 1);
                    if (q < CAP) colIdx[(size_t)e * CAP + q] = v;
                }
            }
        }
        __syncthreads();
        if (threadIdx.x == 0) row_cnt[v] = rc;
    } else {
        // ---- coefficient block (1 block, hidden under the scan) ----
        int t = threadIdx.x;
        // label-branch affine: ab0 = (lt0@lt1).fcw, ab1 = (lb0@lt1+lb1).fcw + fcb
        if (t < 64) {
            float p = 0.f, q = 0.f;
            #pragma unroll 8
            for (int k = 0; k < 64; ++k) {
                float w = lt1[k * 64 + t];
                p += lt0[k] * w;
                q += lb0[k] * w;
            }
            q += lb1[t];
            float pa = p * fcw[t];
            float qb = q * fcw[t];
            #pragma unroll
            for (int off = 32; off; off >>= 1) {
                pa += __shfl_down(pa, off);
                qb += __shfl_down(qb, off);
            }
            if (t == 0) { ab[0] = pa; ab[1] = qb + fcb[0]; }
        }
        // stage A: T = th1 @ w1  (128x128 f32, global bounce)
        #pragma unroll 1
        for (int pass = 0; pass < 4; ++pass) {
            int o = (pass * 256 + t) * 16;
            int r = o >> 7, c0 = o & 127;
            f4 a0 = {0.f,0.f,0.f,0.f}, a1 = a0, a2 = a0, a3 = a0;
            for (int k = 0; k < 128; ++k) {
                float tv = th1[r * 128 + k];
                const f4* wp = reinterpret_cast<const f4*>(w1 + (size_t)k * 128 + c0);
                a0 += tv * wp[0]; a1 += tv * wp[1];
                a2 += tv * wp[2]; a3 += tv * wp[3];
            }
            f4* Tp = reinterpret_cast<f4*>(wsT + o);
            Tp[0] = a0; Tp[1] = a1; Tp[2] = a2; Tp[3] = a3;
        }
        // v1 = w1^T b1
        if (t < 128) {
            float s = 0.f;
            for (int k = 0; k < 128; ++k) s += b1[k] * w1[(size_t)k * 128 + t];
            wsV1[t] = s;
        }
        __syncthreads();
        // stage B: P = T @ w2
        #pragma unroll 1
        for (int pass = 0; pass < 4; ++pass) {
            int o = (pass * 256 + t) * 16;
            int r = o >> 7, c0 = o & 127;
            f4 a0 = {0.f,0.f,0.f,0.f}, a1 = a0, a2 = a0, a3 = a0;
            for (int k = 0; k < 128; ++k) {
                float tv = wsT[r * 128 + k];
                const f4* wp = reinterpret_cast<const f4*>(w2 + (size_t)k * 128 + c0);
                a0 += tv * wp[0]; a1 += tv * wp[1];
                a2 += tv * wp[2]; a3 += tv * wp[3];
            }
            f4* Pp = reinterpret_cast<f4*>(wsP + o);
            Pp[0] = a0; Pp[1] = a1; Pp[2] = a2; Pp[3] = a3;
        }
        // e = w2^T v1 ; d = w2^T bw1 + bw2
        if (t < 128) {
            float s = 0.f;
            for (int j = 0; j < 128; ++j) s += wsV1[j] * w2[(size_t)j * 128 + t];
            evec[t] = s;
        } else {
            int c = t - 128;
            float s = bw2[c];
            for (int j = 0; j < 128; ++j) s += bw1[j] * w2[(size_t)j * 128 + c];
            dvec[c] = s;
        }
    }
}

// ---------------------------------------------------------------------------
// Gather core (R7-proven): 16 nodes/block, 16 lanes/node, 4-deep MLP:
// load int4 of indices, then 4 independent src rows + 4 zsrc before any
// accumulation.
#define ACCUM(r_)                                                              \
    {                                                                          \
        const __half2* h_ = reinterpret_cast<const __half2*>(&(r_));           \
        _Pragma("unroll")                                                      \
        for (int j_ = 0; j_ < 4; ++j_) {                                       \
            float2 f_ = __half22float2(h_[j_]);                                \
            acc[2 * j_]     += f_.x;                                           \
            acc[2 * j_ + 1] += f_.y;                                           \
        }                                                                      \
    }

#define GATHER_CORE(src_, zsrc_)                                               \
    int tid = threadIdx.x;                                                     \
    int node = tid >> 4;                                                       \
    int c8 = tid & 15;                                                         \
    int u = blockIdx.x * 16 + node;                                            \
    int n0 = cnt[u];                                                           \
    float inv = 1.0f / (float)n0;                                              \
    int n = n0 > CAP ? CAP : n0;                                               \
    const int* lst = idx + (size_t)u * CAP;                                    \
    float acc[8] = {0.f, 0.f, 0.f, 0.f, 0.f, 0.f, 0.f, 0.f};                   \
    float zs = 0.f;                                                            \
    int i = 0;                                                                 \
    for (; i + 4 <= n; i += 4) {                                               \
        int4 ss = *reinterpret_cast<const int4*>(lst + i);                     \
        uint4 r0 = *reinterpret_cast<const uint4*>((src_) + (size_t)ss.x * 128 + c8 * 8); \
        uint4 r1 = *reinterpret_cast<const uint4*>((src_) + (size_t)ss.y * 128 + c8 * 8); \
        uint4 r2 = *reinterpret_cast<const uint4*>((src_) + (size_t)ss.z * 128 + c8 * 8); \
        uint4 r3 = *reinterpret_cast<const uint4*>((src_) + (size_t)ss.w * 128 + c8 * 8); \
        float z0 = (zsrc_)[ss.x], z1 = (zsrc_)[ss.y];                          \
        float z2 = (zsrc_)[ss.z], z3 = (zsrc_)[ss.w];                          \
        zs += (z0 + z1) + (z2 + z3);                                           \
        ACCUM(r0); ACCUM(r1); ACCUM(r2); ACCUM(r3);                            \
    }                                                                          \
    for (; i < n; ++i) {                                                       \
        int s = lst[i];                                                        \
        zs += (zsrc_)[s];                                                      \
        uint4 rr = *reinterpret_cast<const uint4*>((src_) + (size_t)s * 128 + c8 * 8); \
        ACCUM(rr);                                                             \
    }

// ---------------------------------------------------------------------------
// Pure gather stage (used for CSC and CSR): fp16 feature agg + scalar label
// agg riding the same list.
__global__ void k_gather(const __half* __restrict__ src, __half* __restrict__ dst,
                         const int* __restrict__ idx, const int* __restrict__ cnt,
                         const float* __restrict__ zsrc, float* __restrict__ zdst) {
    GATHER_CORE(src, zsrc)
    if (c8 == 0) zdst[u] = zs * inv;
    uint4 outv;
    __half2* oh = reinterpret_cast<__half2*>(&outv);
    #pragma unroll
    for (int j = 0; j < 4; ++j)
        oh[j] = __floats2half2_rn(acc[2 * j] * inv, acc[2 * j + 1] * inv);
    *reinterpret_cast<uint4*>(dst + (size_t)u * 128 + c8 * 8) = outv;
}

// ---------------------------------------------------------------------------
// Final kernel: last CSR gather (Z = A^2 F1) + label inline + folded tail:
//   fts = l*(Z@P) + l*e + d -> out[2N..] ; out0 = fts.w3 + bw3 ;
//   out1 = out0 + risk.
__global__ void k_tail(const __half* __restrict__ src,
                       const int* __restrict__ idx, const int* __restrict__ cnt,
                       const float* __restrict__ zsrc, const float* __restrict__ ab,
                       const float* __restrict__ P, const float* __restrict__ evec,
                       const float* __restrict__ dvec,
                       const float* __restrict__ w3, const float* __restrict__ b3,
                       const float* __restrict__ risk, float* __restrict__ out) {
    __shared__ float xs[16][132];
    GATHER_CORE(src, zsrc)
    float l = ab[0] * (zs * inv) + ab[1];
    #pragma unroll
    for (int j = 0; j < 8; ++j) xs[node][c8 * 8 + j] = acc[j] * inv;   // Z row
    __syncthreads();
    f4 a0 = {0.f,0.f,0.f,0.f}, a1 = a0;
    #pragma unroll 8
    for (int k = 0; k < 128; ++k) {
        float zv = xs[node][k];
        a0 += zv * *reinterpret_cast<const f4*>(P + (size_t)k * 128 + c8 * 8);
        a1 += zv * *reinterpret_cast<const f4*>(P + (size_t)k * 128 + c8 * 8 + 4);
    }
    f4 e0 = *reinterpret_cast<const f4*>(evec + c8 * 8);
    f4 e1 = *reinterpret_cast<const f4*>(evec + c8 * 8 + 4);
    f4 d0 = *reinterpret_cast<const f4*>(dvec + c8 * 8);
    f4 d1 = *reinterpret_cast<const f4*>(dvec + c8 * 8 + 4);
    f4 t0 = l * a0 + l * e0 + d0;
    f4 t1 = l * a1 + l * e1 + d1;
    *reinterpret_cast<f4*>(out + 2 * (size_t)N + (size_t)u * 128 + c8 * 8) = t0;
    *reinterpret_cast<f4*>(out + 2 * (size_t)N + (size_t)u * 128 + c8 * 8 + 4) = t1;
    f4 wa = *reinterpret_cast<const f4*>(w3 + c8 * 8);
    f4 wb = *reinterpret_cast<const f4*>(w3 + c8 * 8 + 4);
    float val = t0.x * wa.x + t0.y * wa.y + t0.z * wa.z + t0.w * wa.w
              + t1.x * wb.x + t1.y * wb.y + t1.z * wb.z + t1.w * wb.w;
    #pragma unroll
    for (int off = 8; off; off >>= 1) val += __shfl_down(val, off, 16);
    if (c8 == 0) {
        float o = val + b3[0];
        out[u] = o;
        out[N + u] = o + risk[u];
    }
}

// ---------------------------------------------------------------------------
extern "C" void kernel_launch(void* const* d_in, const int* in_sizes, int n_in,
                              void* d_out, int out_size, void* d_ws, size_t ws_size,
                              hipStream_t stream) {
    const float* x    = (const float*)d_in[0];
    const float* risk = (const float*)d_in[1];
    const float* H    = (const float*)d_in[2];
    const float* th0  = (const float*)d_in[3];
    const float* b0   = (const float*)d_in[4];
    const float* th1  = (const float*)d_in[5];
    const float* b1   = (const float*)d_in[6];
    const float* lt0  = (const float*)d_in[7];
    const float* lb0  = (const float*)d_in[8];
    const float* lt1  = (const float*)d_in[9];
    const float* lb1  = (const float*)d_in[10];
    const float* fcw  = (const float*)d_in[11];
    const float* fcb  = (const float*)d_in[12];
    const float* w1   = (const float*)d_in[13];
    const float* bw1  = (const float*)d_in[14];
    const float* w2   = (const float*)d_in[15];
    const float* bw2  = (const float*)d_in[16];
    const float* w3   = (const float*)d_in[17];
    const float* bw3  = (const float*)d_in[18];
    float* out = (float*)d_out;

    // Workspace layout (KB-aligned)
    char* ws = (char*)d_ws;
    int*   row_cnt = (int*)(ws);                        // 64KB
    int*   col_cnt = (int*)(ws + (1 << 16));            // 64KB
    float* tE      = (float*)(ws + (2 << 16));          // 64KB
    float* tA      = (float*)(ws + (3 << 16));          // 64KB
    float* ab      = (float*)(ws + (4 << 16));          // 2 f
    float* evec    = (float*)(ws + (4 << 16) + 1024);   // 128 f
    float* dvec    = (float*)(ws + (4 << 16) + 2048);   // 128 f
    float* wsV1    = (float*)(ws + (4 << 16) + 3072);   // 128 f
    float* wsT     = (float*)(ws + (5 << 16));          // 64KB
    float* wsP     = (float*)(ws + (6 << 16));          // 64KB
    int*   rowIdx  = (int*)(ws + (7 << 16));                           // 4MB
    int*   colIdx  = (int*)(ws + (7 << 16) + (size_t)N * CAP * 4);     // 4MB
    char*  wsF     = ws + (7 << 16) + 2 * (size_t)N * CAP * 4;
    __half* F1h    = (__half*)(wsF);                                   // 4MB
    __half* F2h    = (__half*)(wsF + (size_t)N * 128 * 2);             // 4MB

    // 1. init (zero col_cnt)
    k_init<<<64, 256, 0, stream>>>(col_cnt);

    // 2. scan H (1 GiB HBM floor) with first GEMM + coefficient folding hidden
    k_mega<<<2048 + N + 1, 256, 0, stream>>>(H, row_cnt, col_cnt, rowIdx, colIdx,
                                             x, th0, b0, F1h,
                                             th1, b1, w1, w2, bw1, bw2,
                                             lt0, lb0, lt1, lb1, fcw, fcb,
                                             ab, wsT, wsP, evec, dvec, wsV1);

    // 3-5. three pure gather stages (CSC, CSR, CSC); label agg rides along
    k_gather<<<N / 16, 256, 0, stream>>>(F1h, F2h, colIdx, col_cnt, risk, tE);
    k_gather<<<N / 16, 256, 0, stream>>>(F2h, F1h, rowIdx, row_cnt, tE, tA);
    k_gather<<<N / 16, 256, 0, stream>>>(F1h, F2h, colIdx, col_cnt, tA, tE);

    // 6. final CSR gather + inline label + folded MLP tail
    k_tail<<<N / 16, 256, 0, stream>>>(F2h, rowIdx, row_cnt, tE, ab,
                                       wsP, evec, dvec, w3, bw3, risk, out);
}

// Round 10
// 449.076 us; speedup vs baseline: 1.2965x; 1.2965x over previous
//
#include <hip/hip_runtime.h>
#include <hip/hip_fp16.h>

#define N 16384
#define CAP 64   // max tracked nnz per row/col of H (Poisson(17) -> max ~40)

typedef float f4 __attribute__((ext_vector_type(4)));

// ---------------------------------------------------------------------------
// init: zero col_cnt.
__global__ void k_init(int* __restrict__ col_cnt) {
    col_cnt[blockIdx.x * 256 + threadIdx.x] = 0;
}

// ---------------------------------------------------------------------------
// Mega kernel:
//   block  0:               coefficient folding (FIRST: starts at t=0, hides
//                           under the scan):
//       P = th1 @ w1 @ w2 (128x128), e = w2^T w1^T b1, d = w2^T bw1 + bw2,
//       ab = collapsed label-branch affine coefficients.
//   blocks [1,2049):        first feature GEMM (x @ th0 + b0 -> F1h, fp16)
//   blocks [2049, 2049+N):  stream one row of dense H each -> CSR + CSC
__global__ void k_mega(const float* __restrict__ H,
                       int* __restrict__ row_cnt, int* __restrict__ col_cnt,
                       int* __restrict__ rowIdx, int* __restrict__ colIdx,
                       const float* __restrict__ x, const float* __restrict__ th0,
                       const float* __restrict__ b0, __half* __restrict__ F1h,
                       const float* __restrict__ th1, const float* __restrict__ b1,
                       const float* __restrict__ w1, const float* __restrict__ w2,
                       const float* __restrict__ bw1, const float* __restrict__ bw2,
                       const float* __restrict__ lt0, const float* __restrict__ lb0,
                       const float* __restrict__ lt1, const float* __restrict__ lb1,
                       const float* __restrict__ fcw, const float* __restrict__ fcb,
                       float* __restrict__ ab, float* __restrict__ wsT,
                       float* __restrict__ wsP, float* __restrict__ evec,
                       float* __restrict__ dvec, float* __restrict__ wsV1) {
    if (blockIdx.x == 0) {
        // ---- coefficient block (1 block, dispatched FIRST, hidden) ----
        int t = threadIdx.x;
        // label-branch affine: ab0 = (lt0@lt1).fcw, ab1 = (lb0@lt1+lb1).fcw + fcb
        if (t < 64) {
            float p = 0.f, q = 0.f;
            #pragma unroll 8
            for (int k = 0; k < 64; ++k) {
                float w = lt1[k * 64 + t];
                p += lt0[k] * w;
                q += lb0[k] * w;
            }
            q += lb1[t];
            float pa = p * fcw[t];
            float qb = q * fcw[t];
            #pragma unroll
            for (int off = 32; off; off >>= 1) {
                pa += __shfl_down(pa, off);
                qb += __shfl_down(qb, off);
            }
            if (t == 0) { ab[0] = pa; ab[1] = qb + fcb[0]; }
        }
        // stage A: T = th1 @ w1  (128x128 f32, global bounce)
        #pragma unroll 1
        for (int pass = 0; pass < 4; ++pass) {
            int o = (pass * 256 + t) * 16;
            int r = o >> 7, c0 = o & 127;
            f4 a0 = {0.f,0.f,0.f,0.f}, a1 = a0, a2 = a0, a3 = a0;
            #pragma unroll 4
            for (int k = 0; k < 128; ++k) {
                float tv = th1[r * 128 + k];
                const f4* wp = reinterpret_cast<const f4*>(w1 + (size_t)k * 128 + c0);
                a0 += tv * wp[0]; a1 += tv * wp[1];
                a2 += tv * wp[2]; a3 += tv * wp[3];
            }
            f4* Tp = reinterpret_cast<f4*>(wsT + o);
            Tp[0] = a0; Tp[1] = a1; Tp[2] = a2; Tp[3] = a3;
        }
        // v1 = w1^T b1  (coalesced across t; unrolled for MLP)
        if (t < 128) {
            float s = 0.f;
            #pragma unroll 4
            for (int k = 0; k < 128; ++k) s += b1[k] * w1[(size_t)k * 128 + t];
            wsV1[t] = s;
        }
        __syncthreads();
        // stage B: P = T @ w2
        #pragma unroll 1
        for (int pass = 0; pass < 4; ++pass) {
            int o = (pass * 256 + t) * 16;
            int r = o >> 7, c0 = o & 127;
            f4 a0 = {0.f,0.f,0.f,0.f}, a1 = a0, a2 = a0, a3 = a0;
            #pragma unroll 4
            for (int k = 0; k < 128; ++k) {
                float tv = wsT[r * 128 + k];
                const f4* wp = reinterpret_cast<const f4*>(w2 + (size_t)k * 128 + c0);
                a0 += tv * wp[0]; a1 += tv * wp[1];
                a2 += tv * wp[2]; a3 += tv * wp[3];
            }
            f4* Pp = reinterpret_cast<f4*>(wsP + o);
            Pp[0] = a0; Pp[1] = a1; Pp[2] = a2; Pp[3] = a3;
        }
        // e = w2^T v1 ; d = w2^T bw1 + bw2
        if (t < 128) {
            float s = 0.f;
            #pragma unroll 4
            for (int j = 0; j < 128; ++j) s += wsV1[j] * w2[(size_t)j * 128 + t];
            evec[t] = s;
        } else {
            int c = t - 128;
            float s = bw2[c];
            #pragma unroll 4
            for (int j = 0; j < 128; ++j) s += bw1[j] * w2[(size_t)j * 128 + c];
            dvec[c] = s;
        }
    } else if (blockIdx.x < 2049) {
        __shared__ float xs[8][128];
        int tid = threadIdx.x;
        int r0 = (blockIdx.x - 1) * 8;
        {
            int i = tid * 4, rr = i >> 7, kk = i & 127;
            f4 raw = *reinterpret_cast<const f4*>(x + (size_t)(r0 + rr) * 128 + kk);
            xs[rr][kk] = raw.x; xs[rr][kk + 1] = raw.y;
            xs[rr][kk + 2] = raw.z; xs[rr][kk + 3] = raw.w;
        }
        __syncthreads();
        int g = tid >> 5, c4 = tid & 31;
        f4 acc = *reinterpret_cast<const f4*>(b0 + c4 * 4);
        #pragma unroll 8
        for (int k = 0; k < 128; ++k) {
            f4 w = *reinterpret_cast<const f4*>(th0 + (size_t)k * 128 + c4 * 4);
            acc += xs[g][k] * w;
        }
        uint2 o;
        __half2* oh = reinterpret_cast<__half2*>(&o);
        oh[0] = __floats2half2_rn(acc.x, acc.y);
        oh[1] = __floats2half2_rn(acc.z, acc.w);
        *reinterpret_cast<uint2*>(F1h + (size_t)(r0 + g) * 128 + c4 * 4) = o;
    } else {
        __shared__ int rc;
        int v = blockIdx.x - 2049;
        if (threadIdx.x == 0) rc = 0;
        __syncthreads();
        const f4* row = reinterpret_cast<const f4*>(H + (size_t)v * N);
        #pragma unroll 4
        for (int i = 0; i < 16; ++i) {
            int idx4 = i * 256 + threadIdx.x;
            f4 val = __builtin_nontemporal_load(row + idx4);
            int e0 = idx4 * 4;
            float vals[4] = {val.x, val.y, val.z, val.w};
            #pragma unroll
            for (int j = 0; j < 4; ++j) {
                if (vals[j] != 0.0f) {
                    int e = e0 + j;
                    int p = atomicAdd(&rc, 1);
                    if (p < CAP) rowIdx[(size_t)v * CAP + p] = e;
                    int q = atomicAdd(&col_cnt[e], 1);
                    if (q < CAP) colIdx[(size_t)e * CAP + q] = v;
                }
            }
        }
        __syncthreads();
        if (threadIdx.x == 0) row_cnt[v] = rc;
    }
}

// ---------------------------------------------------------------------------
// Gather core (R7-proven): 16 nodes/block, 16 lanes/node, 4-deep MLP:
// load int4 of indices, then 4 independent src rows + 4 zsrc before any
// accumulation.
#define ACCUM(r_)                                                              \
    {                                                                          \
        const __half2* h_ = reinterpret_cast<const __half2*>(&(r_));           \
        _Pragma("unroll")                                                      \
        for (int j_ = 0; j_ < 4; ++j_) {                                       \
            float2 f_ = __half22float2(h_[j_]);                                \
            acc[2 * j_]     += f_.x;                                           \
            acc[2 * j_ + 1] += f_.y;                                           \
        }                                                                      \
    }

#define GATHER_CORE(src_, zsrc_)                                               \
    int tid = threadIdx.x;                                                     \
    int node = tid >> 4;                                                       \
    int c8 = tid & 15;                                                         \
    int u = blockIdx.x * 16 + node;                                            \
    int n0 = cnt[u];                                                           \
    float inv = 1.0f / (float)n0;                                              \
    int n = n0 > CAP ? CAP : n0;                                               \
    const int* lst = idx + (size_t)u * CAP;                                    \
    float acc[8] = {0.f, 0.f, 0.f, 0.f, 0.f, 0.f, 0.f, 0.f};                   \
    float zs = 0.f;                                                            \
    int i = 0;                                                                 \
    for (; i + 4 <= n; i += 4) {                                               \
        int4 ss = *reinterpret_cast<const int4*>(lst + i);                     \
        uint4 r0 = *reinterpret_cast<const uint4*>((src_) + (size_t)ss.x * 128 + c8 * 8); \
        uint4 r1 = *reinterpret_cast<const uint4*>((src_) + (size_t)ss.y * 128 + c8 * 8); \
        uint4 r2 = *reinterpret_cast<const uint4*>((src_) + (size_t)ss.z * 128 + c8 * 8); \
        uint4 r3 = *reinterpret_cast<const uint4*>((src_) + (size_t)ss.w * 128 + c8 * 8); \
        float z0 = (zsrc_)[ss.x], z1 = (zsrc_)[ss.y];                          \
        float z2 = (zsrc_)[ss.z], z3 = (zsrc_)[ss.w];                          \
        zs += (z0 + z1) + (z2 + z3);                                           \
        ACCUM(r0); ACCUM(r1); ACCUM(r2); ACCUM(r3);                            \
    }                                                                          \
    for (; i < n; ++i) {                                                       \
        int s = lst[i];                                                        \
        zs += (zsrc_)[s];                                                      \
        uint4 rr = *reinterpret_cast<const uint4*>((src_) + (size_t)s * 128 + c8 * 8); \
        ACCUM(rr);                                                             \
    }

// ---------------------------------------------------------------------------
// Pure gather stage (used for CSC and CSR): fp16 feature agg + scalar label
// agg riding the same list.
__global__ void k_gather(const __half* __restrict__ src, __half* __restrict__ dst,
                         const int* __restrict__ idx, const int* __restrict__ cnt,
                         const float* __restrict__ zsrc, float* __restrict__ zdst) {
    GATHER_CORE(src, zsrc)
    if (c8 == 0) zdst[u] = zs * inv;
    uint4 outv;
    __half2* oh = reinterpret_cast<__half2*>(&outv);
    #pragma unroll
    for (int j = 0; j < 4; ++j)
        oh[j] = __floats2half2_rn(acc[2 * j] * inv, acc[2 * j + 1] * inv);
    *reinterpret_cast<uint4*>(dst + (size_t)u * 128 + c8 * 8) = outv;
}

// ---------------------------------------------------------------------------
// Final kernel: last CSR gather (Z = A^2 F1) + label inline + folded tail:
//   fts = l*(Z@P) + l*e + d -> out[2N..] ; out0 = fts.w3 + bw3 ;
//   out1 = out0 + risk.
__global__ void k_tail(const __half* __restrict__ src,
                       const int* __restrict__ idx, const int* __restrict__ cnt,
                       const float* __restrict__ zsrc, const float* __restrict__ ab,
                       const float* __restrict__ P, const float* __restrict__ evec,
                       const float* __restrict__ dvec,
                       const float* __restrict__ w3, const float* __restrict__ b3,
                       const float* __restrict__ risk, float* __restrict__ out) {
    __shared__ float xs[16][132];
    GATHER_CORE(src, zsrc)
    float l = ab[0] * (zs * inv) + ab[1];
    #pragma unroll
    for (int j = 0; j < 8; ++j) xs[node][c8 * 8 + j] = acc[j] * inv;   // Z row
    __syncthreads();
    f4 a0 = {0.f,0.f,0.f,0.f}, a1 = a0;
    #pragma unroll 8
    for (int k = 0; k < 128; ++k) {
        float zv = xs[node][k];
        a0 += zv * *reinterpret_cast<const f4*>(P + (size_t)k * 128 + c8 * 8);
        a1 += zv * *reinterpret_cast<const f4*>(P + (size_t)k * 128 + c8 * 8 + 4);
    }
    f4 e0 = *reinterpret_cast<const f4*>(evec + c8 * 8);
    f4 e1 = *reinterpret_cast<const f4*>(evec + c8 * 8 + 4);
    f4 d0 = *reinterpret_cast<const f4*>(dvec + c8 * 8);
    f4 d1 = *reinterpret_cast<const f4*>(dvec + c8 * 8 + 4);
    f4 t0 = l * a0 + l * e0 + d0;
    f4 t1 = l * a1 + l * e1 + d1;
    *reinterpret_cast<f4*>(out + 2 * (size_t)N + (size_t)u * 128 + c8 * 8) = t0;
    *reinterpret_cast<f4*>(out + 2 * (size_t)N + (size_t)u * 128 + c8 * 8 + 4) = t1;
    f4 wa = *reinterpret_cast<const f4*>(w3 + c8 * 8);
    f4 wb = *reinterpret_cast<const f4*>(w3 + c8 * 8 + 4);
    float val = t0.x * wa.x + t0.y * wa.y + t0.z * wa.z + t0.w * wa.w
              + t1.x * wb.x + t1.y * wb.y + t1.z * wb.z + t1.w * wb.w;
    #pragma unroll
    for (int off = 8; off; off >>= 1) val += __shfl_down(val, off, 16);
    if (c8 == 0) {
        float o = val + b3[0];
        out[u] = o;
        out[N + u] = o + risk[u];
    }
}

// ---------------------------------------------------------------------------
extern "C" void kernel_launch(void* const* d_in, const int* in_sizes, int n_in,
                              void* d_out, int out_size, void* d_ws, size_t ws_size,
                              hipStream_t stream) {
    const float* x    = (const float*)d_in[0];
    const float* risk = (const float*)d_in[1];
    const float* H    = (const float*)d_in[2];
    const float* th0  = (const float*)d_in[3];
    const float* b0   = (const float*)d_in[4];
    const float* th1  = (const float*)d_in[5];
    const float* b1   = (const float*)d_in[6];
    const float* lt0  = (const float*)d_in[7];
    const float* lb0  = (const float*)d_in[8];
    const float* lt1  = (const float*)d_in[9];
    const float* lb1  = (const float*)d_in[10];
    const float* fcw  = (const float*)d_in[11];
    const float* fcb  = (const float*)d_in[12];
    const float* w1   = (const float*)d_in[13];
    const float* bw1  = (const float*)d_in[14];
    const float* w2   = (const float*)d_in[15];
    const float* bw2  = (const float*)d_in[16];
    const float* w3   = (const float*)d_in[17];
    const float* bw3  = (const float*)d_in[18];
    float* out = (float*)d_out;

    // Workspace layout (KB-aligned)
    char* ws = (char*)d_ws;
    int*   row_cnt = (int*)(ws);                        // 64KB
    int*   col_cnt = (int*)(ws + (1 << 16));            // 64KB
    float* tE      = (float*)(ws + (2 << 16));          // 64KB
    float* tA      = (float*)(ws + (3 << 16));          // 64KB
    float* ab      = (float*)(ws + (4 << 16));          // 2 f
    float* evec    = (float*)(ws + (4 << 16) + 1024);   // 128 f
    float* dvec    = (float*)(ws + (4 << 16) + 2048);   // 128 f
    float* wsV1    = (float*)(ws + (4 << 16) + 3072);   // 128 f
    float* wsT     = (float*)(ws + (5 << 16));          // 64KB
    float* wsP     = (float*)(ws + (6 << 16));          // 64KB
    int*   rowIdx  = (int*)(ws + (7 << 16));                           // 4MB
    int*   colIdx  = (int*)(ws + (7 << 16) + (size_t)N * CAP * 4);     // 4MB
    char*  wsF     = ws + (7 << 16) + 2 * (size_t)N * CAP * 4;
    __half* F1h    = (__half*)(wsF);                                   // 4MB
    __half* F2h    = (__half*)(wsF + (size_t)N * 128 * 2);             // 4MB

    // 1. init (zero col_cnt)
    k_init<<<64, 256, 0, stream>>>(col_cnt);

    // 2. scan H (1 GiB HBM floor); first GEMM + coefficient folding hidden.
    //    Coefficient block is blockIdx 0 so it starts at t~0 and hides.
    k_mega<<<2049 + N, 256, 0, stream>>>(H, row_cnt, col_cnt, rowIdx, colIdx,
                                         x, th0, b0, F1h,
                                         th1, b1, w1, w2, bw1, bw2,
                                         lt0, lb0, lt1, lb1, fcw, fcb,
                                         ab, wsT, wsP, evec, dvec, wsV1);

    // 3-5. three pure gather stages (CSC, CSR, CSC); label agg rides along
    k_gather<<<N / 16, 256, 0, stream>>>(F1h, F2h, colIdx, col_cnt, risk, tE);
    k_gather<<<N / 16, 256, 0, stream>>>(F2h, F1h, rowIdx, row_cnt, tE, tA);
    k_gather<<<N / 16, 256, 0, stream>>>(F1h, F2h, colIdx, col_cnt, tA, tE);

    // 6. final CSR gather + inline label + folded MLP tail
    k_tail<<<N / 16, 256, 0, stream>>>(F2h, rowIdx, row_cnt, tE, ab,
                                       wsP, evec, dvec, w3, bw3, risk, out);
}

// Round 11
// 444.567 us; speedup vs baseline: 1.3097x; 1.0101x over previous
//
#include <hip/hip_runtime.h>
#include <hip/hip_fp16.h>

#define N 16384
#define CAP 64   // max tracked nnz per row/col of H (Poisson(17) -> max ~40)

typedef float f4 __attribute__((ext_vector_type(4)));

// ---------------------------------------------------------------------------
// init: zero col_cnt.
__global__ void k_init(int* __restrict__ col_cnt) {
    col_cnt[blockIdx.x * 256 + threadIdx.x] = 0;
}

// ---------------------------------------------------------------------------
// Mega kernel, VGPR-capped to 128 (4 waves/EU) so the coef branch cannot
// degrade scan occupancy:
//   block 0:                 coefficient folding (low-VGPR version, hides
//                            under the scan from t=0):
//       P = th1 @ w1 @ w2, e = w2^T w1^T b1, d = w2^T bw1 + bw2, ab = label.
//   blocks 1+9k:             first feature GEMM (x @ th0 + b0 -> F1h, fp16)
//   other blocks:            stream one row of dense H -> CSR + CSC
// GEMM blocks are interleaved 1-in-9 so HBM streaming starts at full rate.
__global__ void __launch_bounds__(256, 4)
k_mega(const float* __restrict__ H,
       int* __restrict__ row_cnt, int* __restrict__ col_cnt,
       int* __restrict__ rowIdx, int* __restrict__ colIdx,
       const float* __restrict__ x, const float* __restrict__ th0,
       const float* __restrict__ b0, __half* __restrict__ F1h,
       const float* __restrict__ th1, const float* __restrict__ b1,
       const float* __restrict__ w1, const float* __restrict__ w2,
       const float* __restrict__ bw1, const float* __restrict__ bw2,
       const float* __restrict__ lt0, const float* __restrict__ lb0,
       const float* __restrict__ lt1, const float* __restrict__ lb1,
       const float* __restrict__ fcw, const float* __restrict__ fcb,
       float* __restrict__ ab, float* __restrict__ wsT,
       float* __restrict__ wsP, float* __restrict__ evec,
       float* __restrict__ dvec, float* __restrict__ wsV1) {
    if (blockIdx.x == 0) {
        // ---- coefficient block (1 block, dispatched first, low-VGPR) ----
        int t = threadIdx.x;
        // label-branch affine: ab0=(lt0@lt1).fcw, ab1=(lb0@lt1+lb1).fcw+fcb
        if (t < 64) {
            float p = 0.f, q = 0.f;
            #pragma unroll 4
            for (int k = 0; k < 64; ++k) {
                float w = lt1[k * 64 + t];
                p += lt0[k] * w;
                q += lb0[k] * w;
            }
            q += lb1[t];
            float pa = p * fcw[t];
            float qb = q * fcw[t];
            #pragma unroll
            for (int off = 32; off; off >>= 1) {
                pa += __shfl_down(pa, off);
                qb += __shfl_down(qb, off);
            }
            if (t == 0) { ab[0] = pa; ab[1] = qb + fcb[0]; }
        }
        // stage A: T = th1 @ w1 (2 f4 accumulators, 8 passes, unroll 2)
        #pragma unroll 1
        for (int pass = 0; pass < 8; ++pass) {
            int o = (pass * 256 + t) * 8;
            int r = o >> 7, c0 = o & 127;
            f4 a0 = {0.f,0.f,0.f,0.f}, a1 = a0;
            #pragma unroll 2
            for (int k = 0; k < 128; ++k) {
                float tv = th1[r * 128 + k];
                const f4* wp = reinterpret_cast<const f4*>(w1 + (size_t)k * 128 + c0);
                a0 += tv * wp[0]; a1 += tv * wp[1];
            }
            f4* Tp = reinterpret_cast<f4*>(wsT + o);
            Tp[0] = a0; Tp[1] = a1;
        }
        // v1 = w1^T b1
        if (t < 128) {
            float s = 0.f;
            #pragma unroll 2
            for (int k = 0; k < 128; ++k) s += b1[k] * w1[(size_t)k * 128 + t];
            wsV1[t] = s;
        }
        __syncthreads();
        // stage B: P = T @ w2
        #pragma unroll 1
        for (int pass = 0; pass < 8; ++pass) {
            int o = (pass * 256 + t) * 8;
            int r = o >> 7, c0 = o & 127;
            f4 a0 = {0.f,0.f,0.f,0.f}, a1 = a0;
            #pragma unroll 2
            for (int k = 0; k < 128; ++k) {
                float tv = wsT[r * 128 + k];
                const f4* wp = reinterpret_cast<const f4*>(w2 + (size_t)k * 128 + c0);
                a0 += tv * wp[0]; a1 += tv * wp[1];
            }
            f4* Pp = reinterpret_cast<f4*>(wsP + o);
            Pp[0] = a0; Pp[1] = a1;
        }
        // e = w2^T v1 ; d = w2^T bw1 + bw2
        if (t < 128) {
            float s = 0.f;
            #pragma unroll 2
            for (int j = 0; j < 128; ++j) s += wsV1[j] * w2[(size_t)j * 128 + t];
            evec[t] = s;
        } else {
            int c = t - 128;
            float s = bw2[c];
            #pragma unroll 2
            for (int j = 0; j < 128; ++j) s += bw1[j] * w2[(size_t)j * 128 + c];
            dvec[c] = s;
        }
        return;
    }
    int tb = blockIdx.x - 1;        // 0 .. 18431
    int grp = tb / 9;               // 0 .. 2047
    int rem = tb - grp * 9;         // 0 .. 8
    if (rem == 0) {
        // ---- GEMM block grp: rows [grp*8, grp*8+8) of x @ th0 + b0 ----
        __shared__ float xs[8][128];
        int tid = threadIdx.x;
        int r0 = grp * 8;
        {
            int i = tid * 4, rr = i >> 7, kk = i & 127;
            f4 raw = *reinterpret_cast<const f4*>(x + (size_t)(r0 + rr) * 128 + kk);
            xs[rr][kk] = raw.x; xs[rr][kk + 1] = raw.y;
            xs[rr][kk + 2] = raw.z; xs[rr][kk + 3] = raw.w;
        }
        __syncthreads();
        int g = tid >> 5, c4 = tid & 31;
        f4 acc = *reinterpret_cast<const f4*>(b0 + c4 * 4);
        #pragma unroll 8
        for (int k = 0; k < 128; ++k) {
            f4 w = *reinterpret_cast<const f4*>(th0 + (size_t)k * 128 + c4 * 4);
            acc += xs[g][k] * w;
        }
        uint2 o;
        __half2* oh = reinterpret_cast<__half2*>(&o);
        oh[0] = __floats2half2_rn(acc.x, acc.y);
        oh[1] = __floats2half2_rn(acc.z, acc.w);
        *reinterpret_cast<uint2*>(F1h + (size_t)(r0 + g) * 128 + c4 * 4) = o;
    } else {
        // ---- scan block: row v of H -> CSR/CSC ----
        __shared__ int rc;
        int v = grp * 8 + (rem - 1);   // 0 .. 16383
        if (threadIdx.x == 0) rc = 0;
        __syncthreads();
        const f4* row = reinterpret_cast<const f4*>(H + (size_t)v * N);
        #pragma unroll 4
        for (int i = 0; i < 16; ++i) {
            int idx4 = i * 256 + threadIdx.x;
            f4 val = __builtin_nontemporal_load(row + idx4);
            int e0 = idx4 * 4;
            float vals[4] = {val.x, val.y, val.z, val.w};
            #pragma unroll
            for (int j = 0; j < 4; ++j) {
                if (vals[j] != 0.0f) {
                    int e = e0 + j;
                    int p = atomicAdd(&rc, 1);
                    if (p < CAP) rowIdx[(size_t)v * CAP + p] = e;
                    int q = atomicAdd(&col_cnt[e], 1);
                    if (q < CAP) colIdx[(size_t)e * CAP + q] = v;
                }
            }
        }
        __syncthreads();
        if (threadIdx.x == 0) row_cnt[v] = rc;
    }
}

// ---------------------------------------------------------------------------
// Gather core (R7-proven): 16 nodes/block, 16 lanes/node, 4-deep MLP:
// load int4 of indices, then 4 independent src rows + 4 zsrc before any
// accumulation.
#define ACCUM(r_)                                                              \
    {                                                                          \
        const __half2* h_ = reinterpret_cast<const __half2*>(&(r_));           \
        _Pragma("unroll")                                                      \
        for (int j_ = 0; j_ < 4; ++j_) {                                       \
            float2 f_ = __half22float2(h_[j_]);                                \
            acc[2 * j_]     += f_.x;                                           \
            acc[2 * j_ + 1] += f_.y;                                           \
        }                                                                      \
    }

#define GATHER_CORE(src_, zsrc_)                                               \
    int tid = threadIdx.x;                                                     \
    int node = tid >> 4;                                                       \
    int c8 = tid & 15;                                                         \
    int u = blockIdx.x * 16 + node;                                            \
    int n0 = cnt[u];                                                           \
    float inv = 1.0f / (float)n0;                                              \
    int n = n0 > CAP ? CAP : n0;                                               \
    const int* lst = idx + (size_t)u * CAP;                                    \
    float acc[8] = {0.f, 0.f, 0.f, 0.f, 0.f, 0.f, 0.f, 0.f};                   \
    float zs = 0.f;                                                            \
    int i = 0;                                                                 \
    for (; i + 4 <= n; i += 4) {                                               \
        int4 ss = *reinterpret_cast<const int4*>(lst + i);                     \
        uint4 r0 = *reinterpret_cast<const uint4*>((src_) + (size_t)ss.x * 128 + c8 * 8); \
        uint4 r1 = *reinterpret_cast<const uint4*>((src_) + (size_t)ss.y * 128 + c8 * 8); \
        uint4 r2 = *reinterpret_cast<const uint4*>((src_) + (size_t)ss.z * 128 + c8 * 8); \
        uint4 r3 = *reinterpret_cast<const uint4*>((src_) + (size_t)ss.w * 128 + c8 * 8); \
        float z0 = (zsrc_)[ss.x], z1 = (zsrc_)[ss.y];                          \
        float z2 = (zsrc_)[ss.z], z3 = (zsrc_)[ss.w];                          \
        zs += (z0 + z1) + (z2 + z3);                                           \
        ACCUM(r0); ACCUM(r1); ACCUM(r2); ACCUM(r3);                            \
    }                                                                          \
    for (; i < n; ++i) {                                                       \
        int s = lst[i];                                                        \
        zs += (zsrc_)[s];                                                      \
        uint4 rr = *reinterpret_cast<const uint4*>((src_) + (size_t)s * 128 + c8 * 8); \
        ACCUM(rr);                                                             \
    }

// ---------------------------------------------------------------------------
// Pure gather stage (used for CSC and CSR): fp16 feature agg + scalar label
// agg riding the same list.
__global__ void k_gather(const __half* __restrict__ src, __half* __restrict__ dst,
                         const int* __restrict__ idx, const int* __restrict__ cnt,
                         const float* __restrict__ zsrc, float* __restrict__ zdst) {
    GATHER_CORE(src, zsrc)
    if (c8 == 0) zdst[u] = zs * inv;
    uint4 outv;
    __half2* oh = reinterpret_cast<__half2*>(&outv);
    #pragma unroll
    for (int j = 0; j < 4; ++j)
        oh[j] = __floats2half2_rn(acc[2 * j] * inv, acc[2 * j + 1] * inv);
    *reinterpret_cast<uint4*>(dst + (size_t)u * 128 + c8 * 8) = outv;
}

// ---------------------------------------------------------------------------
// Final kernel: last CSR gather (Z = A^2 F1) + label inline + folded tail:
//   fts = l*(Z@P) + l*e + d -> out[2N..] ; out0 = fts.w3 + bw3 ;
//   out1 = out0 + risk.
__global__ void k_tail(const __half* __restrict__ src,
                       const int* __restrict__ idx, const int* __restrict__ cnt,
                       const float* __restrict__ zsrc, const float* __restrict__ ab,
                       const float* __restrict__ P, const float* __restrict__ evec,
                       const float* __restrict__ dvec,
                       const float* __restrict__ w3, const float* __restrict__ b3,
                       const float* __restrict__ risk, float* __restrict__ out) {
    __shared__ float xs[16][132];
    GATHER_CORE(src, zsrc)
    float l = ab[0] * (zs * inv) + ab[1];
    #pragma unroll
    for (int j = 0; j < 8; ++j) xs[node][c8 * 8 + j] = acc[j] * inv;   // Z row
    __syncthreads();
    f4 a0 = {0.f,0.f,0.f,0.f}, a1 = a0;
    #pragma unroll 8
    for (int k = 0; k < 128; ++k) {
        float zv = xs[node][k];
        a0 += zv * *reinterpret_cast<const f4*>(P + (size_t)k * 128 + c8 * 8);
        a1 += zv * *reinterpret_cast<const f4*>(P + (size_t)k * 128 + c8 * 8 + 4);
    }
    f4 e0 = *reinterpret_cast<const f4*>(evec + c8 * 8);
    f4 e1 = *reinterpret_cast<const f4*>(evec + c8 * 8 + 4);
    f4 d0 = *reinterpret_cast<const f4*>(dvec + c8 * 8);
    f4 d1 = *reinterpret_cast<const f4*>(dvec + c8 * 8 + 4);
    f4 t0 = l * a0 + l * e0 + d0;
    f4 t1 = l * a1 + l * e1 + d1;
    *reinterpret_cast<f4*>(out + 2 * (size_t)N + (size_t)u * 128 + c8 * 8) = t0;
    *reinterpret_cast<f4*>(out + 2 * (size_t)N + (size_t)u * 128 + c8 * 8 + 4) = t1;
    f4 wa = *reinterpret_cast<const f4*>(w3 + c8 * 8);
    f4 wb = *reinterpret_cast<const f4*>(w3 + c8 * 8 + 4);
    float val = t0.x * wa.x + t0.y * wa.y + t0.z * wa.z + t0.w * wa.w
              + t1.x * wb.x + t1.y * wb.y + t1.z * wb.z + t1.w * wb.w;
    #pragma unroll
    for (int off = 8; off; off >>= 1) val += __shfl_down(val, off, 16);
    if (c8 == 0) {
        float o = val + b3[0];
        out[u] = o;
        out[N + u] = o + risk[u];
    }
}

// ---------------------------------------------------------------------------
extern "C" void kernel_launch(void* const* d_in, const int* in_sizes, int n_in,
                              void* d_out, int out_size, void* d_ws, size_t ws_size,
                              hipStream_t stream) {
    const float* x    = (const float*)d_in[0];
    const float* risk = (const float*)d_in[1];
    const float* H    = (const float*)d_in[2];
    const float* th0  = (const float*)d_in[3];
    const float* b0   = (const float*)d_in[4];
    const float* th1  = (const float*)d_in[5];
    const float* b1   = (const float*)d_in[6];
    const float* lt0  = (const float*)d_in[7];
    const float* lb0  = (const float*)d_in[8];
    const float* lt1  = (const float*)d_in[9];
    const float* lb1  = (const float*)d_in[10];
    const float* fcw  = (const float*)d_in[11];
    const float* fcb  = (const float*)d_in[12];
    const float* w1   = (const float*)d_in[13];
    const float* bw1  = (const float*)d_in[14];
    const float* w2   = (const float*)d_in[15];
    const float* bw2  = (const float*)d_in[16];
    const float* w3   = (const float*)d_in[17];
    const float* bw3  = (const float*)d_in[18];
    float* out = (float*)d_out;

    // Workspace layout (KB-aligned)
    char* ws = (char*)d_ws;
    int*   row_cnt = (int*)(ws);                        // 64KB
    int*   col_cnt = (int*)(ws + (1 << 16));            // 64KB
    float* tE      = (float*)(ws + (2 << 16));          // 64KB
    float* tA      = (float*)(ws + (3 << 16));          // 64KB
    float* ab      = (float*)(ws + (4 << 16));          // 2 f
    float* evec    = (float*)(ws + (4 << 16) + 1024);   // 128 f
    float* dvec    = (float*)(ws + (4 << 16) + 2048);   // 128 f
    float* wsV1    = (float*)(ws + (4 << 16) + 3072);   // 128 f
    float* wsT     = (float*)(ws + (5 << 16));          // 64KB
    float* wsP     = (float*)(ws + (6 << 16));          // 64KB
    int*   rowIdx  = (int*)(ws + (7 << 16));                           // 4MB
    int*   colIdx  = (int*)(ws + (7 << 16) + (size_t)N * CAP * 4);     // 4MB
    char*  wsF     = ws + (7 << 16) + 2 * (size_t)N * CAP * 4;
    __half* F1h    = (__half*)(wsF);                                   // 4MB
    __half* F2h    = (__half*)(wsF + (size_t)N * 128 * 2);             // 4MB

    // 1. init (zero col_cnt)
    k_init<<<64, 256, 0, stream>>>(col_cnt);

    // 2. scan H (1 GiB HBM floor); GEMM interleaved 1-in-9, coef block 0.
    k_mega<<<1 + 2048 * 9, 256, 0, stream>>>(H, row_cnt, col_cnt, rowIdx, colIdx,
                                             x, th0, b0, F1h,
                                             th1, b1, w1, w2, bw1, bw2,
                                             lt0, lb0, lt1, lb1, fcw, fcb,
                                             ab, wsT, wsP, evec, dvec, wsV1);

    // 3-5. three pure gather stages (CSC, CSR, CSC); label agg rides along
    k_gather<<<N / 16, 256, 0, stream>>>(F1h, F2h, colIdx, col_cnt, risk, tE);
    k_gather<<<N / 16, 256, 0, stream>>>(F2h, F1h, rowIdx, row_cnt, tE, tA);
    k_gather<<<N / 16, 256, 0, stream>>>(F1h, F2h, colIdx, col_cnt, tA, tE);

    // 6. final CSR gather + inline label + folded MLP tail
    k_tail<<<N / 16, 256, 0, stream>>>(F2h, rowIdx, row_cnt, tE, ab,
                                       wsP, evec, dvec, w3, bw3, risk, out);
}

// Round 12
// 332.495 us; speedup vs baseline: 1.7511x; 1.3371x over previous
//
#include <hip/hip_runtime.h>
#include <hip/hip_fp16.h>

#define N 16384
#define CAP 64   // max tracked nnz per row/col of H (Poisson(17) -> max ~40)

typedef float f4 __attribute__((ext_vector_type(4)));

// ---------------------------------------------------------------------------
// init (runs on an IDLE machine, so the coefficient folding is ~free here):
//   blocks 0..63:  zero col_cnt
//   blocks 64..79: 8 rows each of P = (th1 @ w1) @ w2  (LDS bounce, no sync)
//   block  80:     ab (collapsed label affine), e = w2^T w1^T b1,
//                  d = w2^T bw1 + bw2
__global__ void k_init(int* __restrict__ col_cnt,
                       const float* __restrict__ th1, const float* __restrict__ b1,
                       const float* __restrict__ w1, const float* __restrict__ w2,
                       const float* __restrict__ bw1, const float* __restrict__ bw2,
                       const float* __restrict__ lt0, const float* __restrict__ lb0,
                       const float* __restrict__ lt1, const float* __restrict__ lb1,
                       const float* __restrict__ fcw, const float* __restrict__ fcb,
                       float* __restrict__ ab, float* __restrict__ wsP,
                       float* __restrict__ evec, float* __restrict__ dvec) {
    int t = threadIdx.x;
    if (blockIdx.x < 64) {
        col_cnt[blockIdx.x * 256 + t] = 0;
    } else if (blockIdx.x < 80) {
        // ---- P rows [b*8, b*8+8) ----
        __shared__ float Ts[8][128];
        int b = blockIdx.x - 64;
        int rr = t >> 5;              // 0..7 local row
        int r = b * 8 + rr;           // global row
        int c4 = (t & 31) * 4;        // output col group
        f4 a = {0.f, 0.f, 0.f, 0.f};
        #pragma unroll 4
        for (int k = 0; k < 128; ++k)
            a += th1[(size_t)r * 128 + k] *
                 *reinterpret_cast<const f4*>(w1 + (size_t)k * 128 + c4);
        *reinterpret_cast<f4*>(&Ts[rr][c4]) = a;
        __syncthreads();
        f4 p = {0.f, 0.f, 0.f, 0.f};
        #pragma unroll 4
        for (int k = 0; k < 128; ++k)
            p += Ts[rr][k] *
                 *reinterpret_cast<const f4*>(w2 + (size_t)k * 128 + c4);
        *reinterpret_cast<f4*>(wsP + (size_t)r * 128 + c4) = p;
    } else {
        // ---- scalar/vector coefficients ----
        __shared__ float v1s[128];
        // label-branch affine: ab0=(lt0@lt1).fcw, ab1=(lb0@lt1+lb1).fcw+fcb
        if (t < 64) {
            float p = 0.f, q = 0.f;
            #pragma unroll 4
            for (int k = 0; k < 64; ++k) {
                float w = lt1[k * 64 + t];
                p += lt0[k] * w;
                q += lb0[k] * w;
            }
            q += lb1[t];
            float pa = p * fcw[t];
            float qb = q * fcw[t];
            #pragma unroll
            for (int off = 32; off; off >>= 1) {
                pa += __shfl_down(pa, off);
                qb += __shfl_down(qb, off);
            }
            if (t == 0) { ab[0] = pa; ab[1] = qb + fcb[0]; }
        }
        // v1 = w1^T b1
        if (t < 128) {
            float s = 0.f;
            #pragma unroll 4
            for (int k = 0; k < 128; ++k) s += b1[k] * w1[(size_t)k * 128 + t];
            v1s[t] = s;
        }
        __syncthreads();
        // e = w2^T v1 ; d = w2^T bw1 + bw2
        if (t < 128) {
            float s = 0.f;
            #pragma unroll 4
            for (int j = 0; j < 128; ++j) s += v1s[j] * w2[(size_t)j * 128 + t];
            evec[t] = s;
        } else {
            int c = t - 128;
            float s = bw2[c];
            #pragma unroll 4
            for (int j = 0; j < 128; ++j) s += bw1[j] * w2[(size_t)j * 128 + c];
            dvec[c] = s;
        }
    }
}

// ---------------------------------------------------------------------------
// Mega kernel (exact R7 structure, proven ~200us): blocks [0,2048) do the
// first feature GEMM (x @ th0 + b0 -> F1h, fp16); blocks [2048, 2048+N)
// stream one row of dense H each, building CSR (rowIdx/row_cnt) and CSC
// (colIdx/col_cnt). GEMM hides under the scan's 1 GiB HBM read.
__global__ void k_mega(const float* __restrict__ H,
                       int* __restrict__ row_cnt, int* __restrict__ col_cnt,
                       int* __restrict__ rowIdx, int* __restrict__ colIdx,
                       const float* __restrict__ x, const float* __restrict__ th0,
                       const float* __restrict__ b0, __half* __restrict__ F1h) {
    if (blockIdx.x < 2048) {
        __shared__ float xs[8][128];
        int tid = threadIdx.x;
        int r0 = blockIdx.x * 8;
        {
            int i = tid * 4, rr = i >> 7, kk = i & 127;
            f4 raw = *reinterpret_cast<const f4*>(x + (size_t)(r0 + rr) * 128 + kk);
            xs[rr][kk] = raw.x; xs[rr][kk + 1] = raw.y;
            xs[rr][kk + 2] = raw.z; xs[rr][kk + 3] = raw.w;
        }
        __syncthreads();
        int g = tid >> 5, c4 = tid & 31;
        f4 acc = *reinterpret_cast<const f4*>(b0 + c4 * 4);
        #pragma unroll 8
        for (int k = 0; k < 128; ++k) {
            f4 w = *reinterpret_cast<const f4*>(th0 + (size_t)k * 128 + c4 * 4);
            acc += xs[g][k] * w;
        }
        uint2 o;
        __half2* oh = reinterpret_cast<__half2*>(&o);
        oh[0] = __floats2half2_rn(acc.x, acc.y);
        oh[1] = __floats2half2_rn(acc.z, acc.w);
        *reinterpret_cast<uint2*>(F1h + (size_t)(r0 + g) * 128 + c4 * 4) = o;
    } else {
        __shared__ int rc;
        int v = blockIdx.x - 2048;
        if (threadIdx.x == 0) rc = 0;
        __syncthreads();
        const f4* row = reinterpret_cast<const f4*>(H + (size_t)v * N);
        #pragma unroll 4
        for (int i = 0; i < 16; ++i) {
            int idx4 = i * 256 + threadIdx.x;
            f4 val = __builtin_nontemporal_load(row + idx4);
            int e0 = idx4 * 4;
            float vals[4] = {val.x, val.y, val.z, val.w};
            #pragma unroll
            for (int j = 0; j < 4; ++j) {
                if (vals[j] != 0.0f) {
                    int e = e0 + j;
                    int p = atomicAdd(&rc, 1);
                    if (p < CAP) rowIdx[(size_t)v * CAP + p] = e;
                    int q = atomicAdd(&col_cnt[e], 1);
                    if (q < CAP) colIdx[(size_t)e * CAP + q] = v;
                }
            }
        }
        __syncthreads();
        if (threadIdx.x == 0) row_cnt[v] = rc;
    }
}

// ---------------------------------------------------------------------------
// Gather core (R7-proven): 16 nodes/block, 16 lanes/node, 4-deep MLP:
// load int4 of indices, then 4 independent src rows + 4 zsrc before any
// accumulation.
#define ACCUM(r_)                                                              \
    {                                                                          \
        const __half2* h_ = reinterpret_cast<const __half2*>(&(r_));           \
        _Pragma("unroll")                                                      \
        for (int j_ = 0; j_ < 4; ++j_) {                                       \
            float2 f_ = __half22float2(h_[j_]);                                \
            acc[2 * j_]     += f_.x;                                           \
            acc[2 * j_ + 1] += f_.y;                                           \
        }                                                                      \
    }

#define GATHER_CORE(src_, zsrc_)                                               \
    int tid = threadIdx.x;                                                     \
    int node = tid >> 4;                                                       \
    int c8 = tid & 15;                                                         \
    int u = blockIdx.x * 16 + node;                                            \
    int n0 = cnt[u];                                                           \
    float inv = 1.0f / (float)n0;                                              \
    int n = n0 > CAP ? CAP : n0;                                               \
    const int* lst = idx + (size_t)u * CAP;                                    \
    float acc[8] = {0.f, 0.f, 0.f, 0.f, 0.f, 0.f, 0.f, 0.f};                   \
    float zs = 0.f;                                                            \
    int i = 0;                                                                 \
    for (; i + 4 <= n; i += 4) {                                               \
        int4 ss = *reinterpret_cast<const int4*>(lst + i);                     \
        uint4 r0 = *reinterpret_cast<const uint4*>((src_) + (size_t)ss.x * 128 + c8 * 8); \
        uint4 r1 = *reinterpret_cast<const uint4*>((src_) + (size_t)ss.y * 128 + c8 * 8); \
        uint4 r2 = *reinterpret_cast<const uint4*>((src_) + (size_t)ss.z * 128 + c8 * 8); \
        uint4 r3 = *reinterpret_cast<const uint4*>((src_) + (size_t)ss.w * 128 + c8 * 8); \
        float z0 = (zsrc_)[ss.x], z1 = (zsrc_)[ss.y];                          \
        float z2 = (zsrc_)[ss.z], z3 = (zsrc_)[ss.w];                          \
        zs += (z0 + z1) + (z2 + z3);                                           \
        ACCUM(r0); ACCUM(r1); ACCUM(r2); ACCUM(r3);                            \
    }                                                                          \
    for (; i < n; ++i) {                                                       \
        int s = lst[i];                                                        \
        zs += (zsrc_)[s];                                                      \
        uint4 rr = *reinterpret_cast<const uint4*>((src_) + (size_t)s * 128 + c8 * 8); \
        ACCUM(rr);                                                             \
    }

// ---------------------------------------------------------------------------
// Pure gather stage (used for CSC and CSR): fp16 feature agg + scalar label
// agg riding the same list.
__global__ void k_gather(const __half* __restrict__ src, __half* __restrict__ dst,
                         const int* __restrict__ idx, const int* __restrict__ cnt,
                         const float* __restrict__ zsrc, float* __restrict__ zdst) {
    GATHER_CORE(src, zsrc)
    if (c8 == 0) zdst[u] = zs * inv;
    uint4 outv;
    __half2* oh = reinterpret_cast<__half2*>(&outv);
    #pragma unroll
    for (int j = 0; j < 4; ++j)
        oh[j] = __floats2half2_rn(acc[2 * j] * inv, acc[2 * j + 1] * inv);
    *reinterpret_cast<uint4*>(dst + (size_t)u * 128 + c8 * 8) = outv;
}

// ---------------------------------------------------------------------------
// Final kernel: last CSR gather (Z = A^2 F1) + label inline + folded tail:
//   fts = l*(Z@P) + l*e + d -> out[2N..] ; out0 = fts.w3 + bw3 ;
//   out1 = out0 + risk.
__global__ void k_tail(const __half* __restrict__ src,
                       const int* __restrict__ idx, const int* __restrict__ cnt,
                       const float* __restrict__ zsrc, const float* __restrict__ ab,
                       const float* __restrict__ P, const float* __restrict__ evec,
                       const float* __restrict__ dvec,
                       const float* __restrict__ w3, const float* __restrict__ b3,
                       const float* __restrict__ risk, float* __restrict__ out) {
    __shared__ float xs[16][132];
    GATHER_CORE(src, zsrc)
    float l = ab[0] * (zs * inv) + ab[1];
    #pragma unroll
    for (int j = 0; j < 8; ++j) xs[node][c8 * 8 + j] = acc[j] * inv;   // Z row
    __syncthreads();
    f4 a0 = {0.f,0.f,0.f,0.f}, a1 = a0;
    #pragma unroll 8
    for (int k = 0; k < 128; ++k) {
        float zv = xs[node][k];
        a0 += zv * *reinterpret_cast<const f4*>(P + (size_t)k * 128 + c8 * 8);
        a1 += zv * *reinterpret_cast<const f4*>(P + (size_t)k * 128 + c8 * 8 + 4);
    }
    f4 e0 = *reinterpret_cast<const f4*>(evec + c8 * 8);
    f4 e1 = *reinterpret_cast<const f4*>(evec + c8 * 8 + 4);
    f4 d0 = *reinterpret_cast<const f4*>(dvec + c8 * 8);
    f4 d1 = *reinterpret_cast<const f4*>(dvec + c8 * 8 + 4);
    f4 t0 = l * a0 + l * e0 + d0;
    f4 t1 = l * a1 + l * e1 + d1;
    *reinterpret_cast<f4*>(out + 2 * (size_t)N + (size_t)u * 128 + c8 * 8) = t0;
    *reinterpret_cast<f4*>(out + 2 * (size_t)N + (size_t)u * 128 + c8 * 8 + 4) = t1;
    f4 wa = *reinterpret_cast<const f4*>(w3 + c8 * 8);
    f4 wb = *reinterpret_cast<const f4*>(w3 + c8 * 8 + 4);
    float val = t0.x * wa.x + t0.y * wa.y + t0.z * wa.z + t0.w * wa.w
              + t1.x * wb.x + t1.y * wb.y + t1.z * wb.z + t1.w * wb.w;
    #pragma unroll
    for (int off = 8; off; off >>= 1) val += __shfl_down(val, off, 16);
    if (c8 == 0) {
        float o = val + b3[0];
        out[u] = o;
        out[N + u] = o + risk[u];
    }
}

// ---------------------------------------------------------------------------
extern "C" void kernel_launch(void* const* d_in, const int* in_sizes, int n_in,
                              void* d_out, int out_size, void* d_ws, size_t ws_size,
                              hipStream_t stream) {
    const float* x    = (const float*)d_in[0];
    const float* risk = (const float*)d_in[1];
    const float* H    = (const float*)d_in[2];
    const float* th0  = (const float*)d_in[3];
    const float* b0   = (const float*)d_in[4];
    const float* th1  = (const float*)d_in[5];
    const float* b1   = (const float*)d_in[6];
    const float* lt0  = (const float*)d_in[7];
    const float* lb0  = (const float*)d_in[8];
    const float* lt1  = (const float*)d_in[9];
    const float* lb1  = (const float*)d_in[10];
    const float* fcw  = (const float*)d_in[11];
    const float* fcb  = (const float*)d_in[12];
    const float* w1   = (const float*)d_in[13];
    const float* bw1  = (const float*)d_in[14];
    const float* w2   = (const float*)d_in[15];
    const float* bw2  = (const float*)d_in[16];
    const float* w3   = (const float*)d_in[17];
    const float* bw3  = (const float*)d_in[18];
    float* out = (float*)d_out;

    // Workspace layout (KB-aligned)
    char* ws = (char*)d_ws;
    int*   row_cnt = (int*)(ws);                        // 64KB
    int*   col_cnt = (int*)(ws + (1 << 16));            // 64KB
    float* tE      = (float*)(ws + (2 << 16));          // 64KB
    float* tA      = (float*)(ws + (3 << 16));          // 64KB
    float* ab      = (float*)(ws + (4 << 16));          // 2 f
    float* evec    = (float*)(ws + (4 << 16) + 1024);   // 128 f
    float* dvec    = (float*)(ws + (4 << 16) + 2048);   // 128 f
    float* wsP     = (float*)(ws + (6 << 16));          // 64KB
    int*   rowIdx  = (int*)(ws + (7 << 16));                           // 4MB
    int*   colIdx  = (int*)(ws + (7 << 16) + (size_t)N * CAP * 4);     // 4MB
    char*  wsF     = ws + (7 << 16) + 2 * (size_t)N * CAP * 4;
    __half* F1h    = (__half*)(wsF);                                   // 4MB
    __half* F2h    = (__half*)(wsF + (size_t)N * 128 * 2);             // 4MB

    // 1. init: zero col_cnt + ALL coefficient folding (machine idle -> ~free)
    k_init<<<81, 256, 0, stream>>>(col_cnt, th1, b1, w1, w2, bw1, bw2,
                                   lt0, lb0, lt1, lb1, fcw, fcb,
                                   ab, wsP, evec, dvec);

    // 2. scan H (1 GiB HBM floor) with first GEMM hidden under it (R7 form)
    k_mega<<<2048 + N, 256, 0, stream>>>(H, row_cnt, col_cnt, rowIdx, colIdx,
                                         x, th0, b0, F1h);

    // 3-5. three pure gather stages (CSC, CSR, CSC); label agg rides along
    k_gather<<<N / 16, 256, 0, stream>>>(F1h, F2h, colIdx, col_cnt, risk, tE);
    k_gather<<<N / 16, 256, 0, stream>>>(F2h, F1h, rowIdx, row_cnt, tE, tA);
    k_gather<<<N / 16, 256, 0, stream>>>(F1h, F2h, colIdx, col_cnt, tA, tE);

    // 6. final CSR gather + inline label + folded MLP tail
    k_tail<<<N / 16, 256, 0, stream>>>(F2h, rowIdx, row_cnt, tE, ab,
                                       wsP, evec, dvec, w3, bw3, risk, out);
}

// Round 13
// 324.289 us; speedup vs baseline: 1.7954x; 1.0253x over previous
//
#include <hip/hip_runtime.h>
#include <hip/hip_fp16.h>

#define N 16384
#define CAP 64   // max tracked nnz per row/col of H (Poisson(17) -> max ~40)

typedef float f4 __attribute__((ext_vector_type(4)));

// ---------------------------------------------------------------------------
// init (runs on an IDLE machine, so the coefficient folding is ~free here):
//   blocks 0..63:  zero col_cnt
//   blocks 64..79: 8 rows each of P = (th1 @ w1) @ w2  (LDS bounce, no sync)
//   block  80:     ab (collapsed label affine), e = w2^T w1^T b1,
//                  d = w2^T bw1 + bw2
__global__ void k_init(int* __restrict__ col_cnt,
                       const float* __restrict__ th1, const float* __restrict__ b1,
                       const float* __restrict__ w1, const float* __restrict__ w2,
                       const float* __restrict__ bw1, const float* __restrict__ bw2,
                       const float* __restrict__ lt0, const float* __restrict__ lb0,
                       const float* __restrict__ lt1, const float* __restrict__ lb1,
                       const float* __restrict__ fcw, const float* __restrict__ fcb,
                       float* __restrict__ ab, float* __restrict__ wsP,
                       float* __restrict__ evec, float* __restrict__ dvec) {
    int t = threadIdx.x;
    if (blockIdx.x < 64) {
        col_cnt[blockIdx.x * 256 + t] = 0;
    } else if (blockIdx.x < 80) {
        // ---- P rows [b*8, b*8+8) ----
        __shared__ float Ts[8][128];
        int b = blockIdx.x - 64;
        int rr = t >> 5;              // 0..7 local row
        int r = b * 8 + rr;           // global row
        int c4 = (t & 31) * 4;        // output col group
        f4 a = {0.f, 0.f, 0.f, 0.f};
        #pragma unroll 4
        for (int k = 0; k < 128; ++k)
            a += th1[(size_t)r * 128 + k] *
                 *reinterpret_cast<const f4*>(w1 + (size_t)k * 128 + c4);
        *reinterpret_cast<f4*>(&Ts[rr][c4]) = a;
        __syncthreads();
        f4 p = {0.f, 0.f, 0.f, 0.f};
        #pragma unroll 4
        for (int k = 0; k < 128; ++k)
            p += Ts[rr][k] *
                 *reinterpret_cast<const f4*>(w2 + (size_t)k * 128 + c4);
        *reinterpret_cast<f4*>(wsP + (size_t)r * 128 + c4) = p;
    } else {
        // ---- scalar/vector coefficients ----
        __shared__ float v1s[128];
        // label-branch affine: ab0=(lt0@lt1).fcw, ab1=(lb0@lt1+lb1).fcw+fcb
        if (t < 64) {
            float p = 0.f, q = 0.f;
            #pragma unroll 4
            for (int k = 0; k < 64; ++k) {
                float w = lt1[k * 64 + t];
                p += lt0[k] * w;
                q += lb0[k] * w;
            }
            q += lb1[t];
            float pa = p * fcw[t];
            float qb = q * fcw[t];
            #pragma unroll
            for (int off = 32; off; off >>= 1) {
                pa += __shfl_down(pa, off);
                qb += __shfl_down(qb, off);
            }
            if (t == 0) { ab[0] = pa; ab[1] = qb + fcb[0]; }
        }
        // v1 = w1^T b1
        if (t < 128) {
            float s = 0.f;
            #pragma unroll 4
            for (int k = 0; k < 128; ++k) s += b1[k] * w1[(size_t)k * 128 + t];
            v1s[t] = s;
        }
        __syncthreads();
        // e = w2^T v1 ; d = w2^T bw1 + bw2
        if (t < 128) {
            float s = 0.f;
            #pragma unroll 4
            for (int j = 0; j < 128; ++j) s += v1s[j] * w2[(size_t)j * 128 + t];
            evec[t] = s;
        } else {
            int c = t - 128;
            float s = bw2[c];
            #pragma unroll 4
            for (int j = 0; j < 128; ++j) s += bw1[j] * w2[(size_t)j * 128 + c];
            dvec[c] = s;
        }
    }
}

// ---------------------------------------------------------------------------
// Mega kernel (scan blocks FIRST so HBM streaming starts immediately; GEMM
// blocks dispatched last fill the scan's drain tail):
//   blocks [0,N):        stream one row of dense H each -> CSR + CSC
//   blocks [N, N+2048):  first feature GEMM (x @ th0 + b0 -> F1h, fp16)
__global__ void k_mega(const float* __restrict__ H,
                       int* __restrict__ row_cnt, int* __restrict__ col_cnt,
                       int* __restrict__ rowIdx, int* __restrict__ colIdx,
                       const float* __restrict__ x, const float* __restrict__ th0,
                       const float* __restrict__ b0, __half* __restrict__ F1h) {
    if (blockIdx.x < N) {
        __shared__ int rc;
        int v = blockIdx.x;
        if (threadIdx.x == 0) rc = 0;
        __syncthreads();
        const f4* row = reinterpret_cast<const f4*>(H + (size_t)v * N);
        #pragma unroll 4
        for (int i = 0; i < 16; ++i) {
            int idx4 = i * 256 + threadIdx.x;
            f4 val = __builtin_nontemporal_load(row + idx4);
            int e0 = idx4 * 4;
            float vals[4] = {val.x, val.y, val.z, val.w};
            #pragma unroll
            for (int j = 0; j < 4; ++j) {
                if (vals[j] != 0.0f) {
                    int e = e0 + j;
                    int p = atomicAdd(&rc, 1);
                    if (p < CAP) rowIdx[(size_t)v * CAP + p] = e;
                    int q = atomicAdd(&col_cnt[e], 1);
                    if (q < CAP) colIdx[(size_t)e * CAP + q] = v;
                }
            }
        }
        __syncthreads();
        if (threadIdx.x == 0) row_cnt[v] = rc;
    } else {
        __shared__ float xs[8][128];
        int tid = threadIdx.x;
        int r0 = (blockIdx.x - N) * 8;
        {
            int i = tid * 4, rr = i >> 7, kk = i & 127;
            f4 raw = *reinterpret_cast<const f4*>(x + (size_t)(r0 + rr) * 128 + kk);
            xs[rr][kk] = raw.x; xs[rr][kk + 1] = raw.y;
            xs[rr][kk + 2] = raw.z; xs[rr][kk + 3] = raw.w;
        }
        __syncthreads();
        int g = tid >> 5, c4 = tid & 31;
        f4 acc = *reinterpret_cast<const f4*>(b0 + c4 * 4);
        #pragma unroll 8
        for (int k = 0; k < 128; ++k) {
            f4 w = *reinterpret_cast<const f4*>(th0 + (size_t)k * 128 + c4 * 4);
            acc += xs[g][k] * w;
        }
        uint2 o;
        __half2* oh = reinterpret_cast<__half2*>(&o);
        oh[0] = __floats2half2_rn(acc.x, acc.y);
        oh[1] = __floats2half2_rn(acc.z, acc.w);
        *reinterpret_cast<uint2*>(F1h + (size_t)(r0 + g) * 128 + c4 * 4) = o;
    }
}

// ---------------------------------------------------------------------------
// Gather core (R7-proven): 16 nodes/block, 16 lanes/node, 4-deep MLP:
// load int4 of indices, then 4 independent src rows + 4 zsrc before any
// accumulation.
#define ACCUM(r_)                                                              \
    {                                                                          \
        const __half2* h_ = reinterpret_cast<const __half2*>(&(r_));           \
        _Pragma("unroll")                                                      \
        for (int j_ = 0; j_ < 4; ++j_) {                                       \
            float2 f_ = __half22float2(h_[j_]);                                \
            acc[2 * j_]     += f_.x;                                           \
            acc[2 * j_ + 1] += f_.y;                                           \
        }                                                                      \
    }

#define GATHER_CORE(src_, zsrc_)                                               \
    int tid = threadIdx.x;                                                     \
    int node = tid >> 4;                                                       \
    int c8 = tid & 15;                                                         \
    int u = blockIdx.x * 16 + node;                                            \
    int n0 = cnt[u];                                                           \
    float inv = 1.0f / (float)n0;                                              \
    int n = n0 > CAP ? CAP : n0;                                               \
    const int* lst = idx + (size_t)u * CAP;                                    \
    float acc[8] = {0.f, 0.f, 0.f, 0.f, 0.f, 0.f, 0.f, 0.f};                   \
    float zs = 0.f;                                                            \
    int i = 0;                                                                 \
    for (; i + 4 <= n; i += 4) {                                               \
        int4 ss = *reinterpret_cast<const int4*>(lst + i);                     \
        uint4 r0 = *reinterpret_cast<const uint4*>((src_) + (size_t)ss.x * 128 + c8 * 8); \
        uint4 r1 = *reinterpret_cast<const uint4*>((src_) + (size_t)ss.y * 128 + c8 * 8); \
        uint4 r2 = *reinterpret_cast<const uint4*>((src_) + (size_t)ss.z * 128 + c8 * 8); \
        uint4 r3 = *reinterpret_cast<const uint4*>((src_) + (size_t)ss.w * 128 + c8 * 8); \
        float z0 = (zsrc_)[ss.x], z1 = (zsrc_)[ss.y];                          \
        float z2 = (zsrc_)[ss.z], z3 = (zsrc_)[ss.w];                          \
        zs += (z0 + z1) + (z2 + z3);                                           \
        ACCUM(r0); ACCUM(r1); ACCUM(r2); ACCUM(r3);                            \
    }                                                                          \
    for (; i < n; ++i) {                                                       \
        int s = lst[i];                                                        \
        zs += (zsrc_)[s];                                                      \
        uint4 rr = *reinterpret_cast<const uint4*>((src_) + (size_t)s * 128 + c8 * 8); \
        ACCUM(rr);                                                             \
    }

// ---------------------------------------------------------------------------
// Pure gather stage (used for CSC and CSR): fp16 feature agg + scalar label
// agg riding the same list.
__global__ void k_gather(const __half* __restrict__ src, __half* __restrict__ dst,
                         const int* __restrict__ idx, const int* __restrict__ cnt,
                         const float* __restrict__ zsrc, float* __restrict__ zdst) {
    GATHER_CORE(src, zsrc)
    if (c8 == 0) zdst[u] = zs * inv;
    uint4 outv;
    __half2* oh = reinterpret_cast<__half2*>(&outv);
    #pragma unroll
    for (int j = 0; j < 4; ++j)
        oh[j] = __floats2half2_rn(acc[2 * j] * inv, acc[2 * j + 1] * inv);
    *reinterpret_cast<uint4*>(dst + (size_t)u * 128 + c8 * 8) = outv;
}

// ---------------------------------------------------------------------------
// Final kernel: last CSR gather (Z = A^2 F1) + label inline + folded tail:
//   fts = l*(Z@P) + l*e + d -> out[2N..] ; out0 = fts.w3 + bw3 ;
//   out1 = out0 + risk.
__global__ void k_tail(const __half* __restrict__ src,
                       const int* __restrict__ idx, const int* __restrict__ cnt,
                       const float* __restrict__ zsrc, const float* __restrict__ ab,
                       const float* __restrict__ P, const float* __restrict__ evec,
                       const float* __restrict__ dvec,
                       const float* __restrict__ w3, const float* __restrict__ b3,
                       const float* __restrict__ risk, float* __restrict__ out) {
    __shared__ float xs[16][132];
    GATHER_CORE(src, zsrc)
    float l = ab[0] * (zs * inv) + ab[1];
    #pragma unroll
    for (int j = 0; j < 8; ++j) xs[node][c8 * 8 + j] = acc[j] * inv;   // Z row
    __syncthreads();
    f4 a0 = {0.f,0.f,0.f,0.f}, a1 = a0;
    #pragma unroll 8
    for (int k = 0; k < 128; ++k) {
        float zv = xs[node][k];
        a0 += zv * *reinterpret_cast<const f4*>(P + (size_t)k * 128 + c8 * 8);
        a1 += zv * *reinterpret_cast<const f4*>(P + (size_t)k * 128 + c8 * 8 + 4);
    }
    f4 e0 = *reinterpret_cast<const f4*>(evec + c8 * 8);
    f4 e1 = *reinterpret_cast<const f4*>(evec + c8 * 8 + 4);
    f4 d0 = *reinterpret_cast<const f4*>(dvec + c8 * 8);
    f4 d1 = *reinterpret_cast<const f4*>(dvec + c8 * 8 + 4);
    f4 t0 = l * a0 + l * e0 + d0;
    f4 t1 = l * a1 + l * e1 + d1;
    *reinterpret_cast<f4*>(out + 2 * (size_t)N + (size_t)u * 128 + c8 * 8) = t0;
    *reinterpret_cast<f4*>(out + 2 * (size_t)N + (size_t)u * 128 + c8 * 8 + 4) = t1;
    f4 wa = *reinterpret_cast<const f4*>(w3 + c8 * 8);
    f4 wb = *reinterpret_cast<const f4*>(w3 + c8 * 8 + 4);
    float val = t0.x * wa.x + t0.y * wa.y + t0.z * wa.z + t0.w * wa.w
              + t1.x * wb.x + t1.y * wb.y + t1.z * wb.z + t1.w * wb.w;
    #pragma unroll
    for (int off = 8; off; off >>= 1) val += __shfl_down(val, off, 16);
    if (c8 == 0) {
        float o = val + b3[0];
        out[u] = o;
        out[N + u] = o + risk[u];
    }
}

// ---------------------------------------------------------------------------
extern "C" void kernel_launch(void* const* d_in, const int* in_sizes, int n_in,
                              void* d_out, int out_size, void* d_ws, size_t ws_size,
                              hipStream_t stream) {
    const float* x    = (const float*)d_in[0];
    const float* risk = (const float*)d_in[1];
    const float* H    = (const float*)d_in[2];
    const float* th0  = (const float*)d_in[3];
    const float* b0   = (const float*)d_in[4];
    const float* th1  = (const float*)d_in[5];
    const float* b1   = (const float*)d_in[6];
    const float* lt0  = (const float*)d_in[7];
    const float* lb0  = (const float*)d_in[8];
    const float* lt1  = (const float*)d_in[9];
    const float* lb1  = (const float*)d_in[10];
    const float* fcw  = (const float*)d_in[11];
    const float* fcb  = (const float*)d_in[12];
    const float* w1   = (const float*)d_in[13];
    const float* bw1  = (const float*)d_in[14];
    const float* w2   = (const float*)d_in[15];
    const float* bw2  = (const float*)d_in[16];
    const float* w3   = (const float*)d_in[17];
    const float* bw3  = (const float*)d_in[18];
    float* out = (float*)d_out;

    // Workspace layout (KB-aligned)
    char* ws = (char*)d_ws;
    int*   row_cnt = (int*)(ws);                        // 64KB
    int*   col_cnt = (int*)(ws + (1 << 16));            // 64KB
    float* tE      = (float*)(ws + (2 << 16));          // 64KB
    float* tA      = (float*)(ws + (3 << 16));          // 64KB
    float* ab      = (float*)(ws + (4 << 16));          // 2 f
    float* evec    = (float*)(ws + (4 << 16) + 1024);   // 128 f
    float* dvec    = (float*)(ws + (4 << 16) + 2048);   // 128 f
    float* wsP     = (float*)(ws + (6 << 16));          // 64KB
    int*   rowIdx  = (int*)(ws + (7 << 16));                           // 4MB
    int*   colIdx  = (int*)(ws + (7 << 16) + (size_t)N * CAP * 4);     // 4MB
    char*  wsF     = ws + (7 << 16) + 2 * (size_t)N * CAP * 4;
    __half* F1h    = (__half*)(wsF);                                   // 4MB
    __half* F2h    = (__half*)(wsF + (size_t)N * 128 * 2);             // 4MB

    // 1. init: zero col_cnt + ALL coefficient folding (machine idle -> ~free)
    k_init<<<81, 256, 0, stream>>>(col_cnt, th1, b1, w1, w2, bw1, bw2,
                                   lt0, lb0, lt1, lb1, fcw, fcb,
                                   ab, wsP, evec, dvec);

    // 2. scan H (1 GiB HBM floor, scan blocks first); GEMM fills drain tail
    k_mega<<<N + 2048, 256, 0, stream>>>(H, row_cnt, col_cnt, rowIdx, colIdx,
                                         x, th0, b0, F1h);

    // 3-5. three pure gather stages (CSC, CSR, CSC); label agg rides along
    k_gather<<<N / 16, 256, 0, stream>>>(F1h, F2h, colIdx, col_cnt, risk, tE);
    k_gather<<<N / 16, 256, 0, stream>>>(F2h, F1h, rowIdx, row_cnt, tE, tA);
    k_gather<<<N / 16, 256, 0, stream>>>(F1h, F2h, colIdx, col_cnt, tA, tE);

    // 6. final CSR gather + inline label + folded MLP tail
    k_tail<<<N / 16, 256, 0, stream>>>(F2h, rowIdx, row_cnt, tE, ab,
                                       wsP, evec, dvec, w3, bw3, risk, out);
}